// Round 4
// baseline (318.613 us; speedup 1.0000x reference)
//
#include <hip/hip_runtime.h>

// GrahamLoss: B=16, C=128, HW=16384, fp32 in, fp32[16] out.
//
// v5: two-pass repack. All prior variants (BK 128/256/512 B, 2-4 blocks/CU,
// never-drain pipeline) capped at ~2.7 TB/s delivered: 64KB-strided row reads
// with <=512B per visit thrash DRAM pages regardless of occupancy. Fix:
//  Pass A (pack_k): fully-contiguous fp32 streaming read (16 KB/row sequential,
//    nontemporal), convert bf16, write stage-major packed layout
//    [g][ST(256)][row(128)][swizzled 128 B] = the exact LDS image pass B wants.
//  Pass B (gram_packed_k): v1's proven MFMA loop; staging = 4x global_load_lds
//    of a CONTIGUOUS 16 KB (likely L3-hot) stage. Same f2bf + k-order as the
//    passing kernel -> identical numerics.
//  Fallback to direct strided kernel if ws < 160 MiB (ws >= 64 MiB proven).

typedef __attribute__((ext_vector_type(8))) short short8;
typedef __attribute__((ext_vector_type(4))) short short4v;
typedef __attribute__((ext_vector_type(4))) float f32x4;

#define CC 128
#define NN 16384

// fp32 -> bf16 round-to-nearest-even (bit math; inputs are finite)
__device__ __forceinline__ short f2bf(float x) {
    unsigned u = __builtin_bit_cast(unsigned, x);
    u += 0x7fffu + ((u >> 16) & 1u);
    return (short)(u >> 16);
}

// ---------------- Pass A: fp32 row-major -> bf16 stage-major packed ----------------
// packed: [g(32)][ST(256)][row(128)][chunk(8), phys = c ^ (row&7)][8 bf16]; stage = 16 KB.
// Block: (rg fastest -> co-dispatched rowgroups densify writes per stage region).
__global__ __launch_bounds__(512, 2) void pack_k(
    const float* __restrict__ f0, const float* __restrict__ f1,
    short* __restrict__ packed)
{
    const int bx = blockIdx.x;      // 512 blocks
    const int rg = bx & 3;          // row group (32 rows)
    const int kr = (bx >> 2) & 3;   // col quarter (4096 f32 = 16 KB/row)
    const int g  = bx >> 4;         // gram id 0..31

    const float* src  = (g & 1) ? f1 : f0;
    const float* base = src + (size_t)(g >> 1) * ((size_t)CC * NN);

    const int t    = threadIdx.x;
    const int lane = t & 63;
    const int w    = t >> 6;        // wave 0..7, each owns 4 rows

    // lane -> position within a 1 KB (256 f32) read window:
    // lane holds f32s [lane*4, lane*4+4): stage-local sl = lane>>4, chunk c, half hf.
    const int c  = (lane & 15) >> 1;
    const int hf = lane & 1;
    const int sl = lane >> 4;

    char* pg = (char*)packed + (size_t)g * 256 * 16384;

    for (int rr = 0; rr < 4; ++rr) {
        const int row = rg * 32 + w * 4 + rr;
        const float* rp = base + (size_t)row * NN + kr * 4096 + lane * 4;
        const size_t rowoff = (size_t)row * 128 + (size_t)(((c ^ (row & 7)) * 16) + hf * 8);
        #pragma unroll 4
        for (int ii = 0; ii < 16; ++ii) {   // 16 x 1 KB sequential per row
            f32x4 v = __builtin_nontemporal_load((const f32x4*)(rp + (size_t)ii * 256));
            short4v b = { f2bf(v[0]), f2bf(v[1]), f2bf(v[2]), f2bf(v[3]) };
            const int ST = kr * 64 + ii * 4 + sl;
            *(short4v*)(pg + (size_t)ST * 16384 + rowoff) = b;
        }
    }
}

// ---------------- Pass B: gram from packed (contiguous 16 KB stages) ----------------
__global__ __launch_bounds__(256, 2) void gram_packed_k(
    const short* __restrict__ packed, float* __restrict__ partials, int S, int nst)
{
    __shared__ short lds[2][CC * 64];   // double-buffered 16 KB stage images

    const int tid = threadIdx.x;
    const int bx  = blockIdx.x;
    const int g   = bx & 31;
    const int s   = bx >> 5;

    const char* pk = (const char*)packed + (size_t)(g * 256 + s * nst) * 16384;

    const int lane = tid & 63;
    const int w    = tid >> 6;
    const int m0   = (w & 1) * 64;
    const int n0   = (w >> 1) * 64;
    const int lr   = lane & 15;
    const int lk   = lane >> 4;

    f32x4 acc[4][4];
    #pragma unroll
    for (int i = 0; i < 4; ++i)
        #pragma unroll
        for (int j = 0; j < 4; ++j)
            acc[i][j] = (f32x4){0.f, 0.f, 0.f, 0.f};

    auto issue = [&](int j, int buf) {
        const char* sb = pk + (size_t)j * 16384;
        #pragma unroll
        for (int i = 0; i < 4; ++i) {
            const int off = (w * 4 + i) * 1024;             // bytes; wave-uniform
            __builtin_amdgcn_global_load_lds(
                (const __attribute__((address_space(1))) void*)(sb + off + lane * 16),
                (__attribute__((address_space(3))) void*)((char*)&lds[buf][0] + off),
                16, 0, 0);
        }
    };

    auto compute = [&](int buf) {
        #pragma unroll
        for (int ks = 0; ks < 2; ++ks) {
            short8 af[4], bfr[4];
            const int cb = ks * 4 + lk;
            #pragma unroll
            for (int i = 0; i < 4; ++i) {
                int r = m0 + i * 16 + lr;
                af[i] = *(const short8*)&lds[buf][r * 64 + ((cb ^ (r & 7)) * 8)];
            }
            #pragma unroll
            for (int i = 0; i < 4; ++i) {
                int r = n0 + i * 16 + lr;
                bfr[i] = *(const short8*)&lds[buf][r * 64 + ((cb ^ (r & 7)) * 8)];
            }
            #pragma unroll
            for (int mi = 0; mi < 4; ++mi)
                #pragma unroll
                for (int ni = 0; ni < 4; ++ni)
                    acc[mi][ni] = __builtin_amdgcn_mfma_f32_16x16x32_bf16(
                        af[mi], bfr[ni], acc[mi][ni], 0, 0, 0);
        }
    };

    issue(0, 0);
    __syncthreads();
    for (int j = 0; j < nst; ++j) {
        if (j + 1 < nst) issue(j + 1, (j + 1) & 1);
        compute(j & 1);
        __syncthreads();
    }

    float* op = partials + ((size_t)g * S + s) * (CC * CC);
    #pragma unroll
    for (int mi = 0; mi < 4; ++mi)
        #pragma unroll
        for (int ni = 0; ni < 4; ++ni)
            #pragma unroll
            for (int i = 0; i < 4; ++i) {
                int row = m0 + mi * 16 + lk * 4 + i;
                int col = n0 + ni * 16 + lr;
                op[row * CC + col] = acc[mi][ni][i];
            }
}

// ---------------- Fallback: direct strided gram (proven r0 kernel) ----------------
__global__ __launch_bounds__(256, 2) void gram_direct_k(
    const float* __restrict__ f0, const float* __restrict__ f1,
    float* __restrict__ partials, int S, int Kc, int nst)
{
    __shared__ short lds[2][CC * 64];

    const int tid = threadIdx.x;
    const int bx  = blockIdx.x;
    const int g   = bx & 31;
    const int s   = bx >> 5;

    const float* src  = (g & 1) ? f1 : f0;
    const float* base = src + (size_t)(g >> 1) * ((size_t)CC * NN) + (size_t)s * Kc;

    const int srow = tid >> 3;
    const int scb  = tid & 7;
    const float* gp = base + (size_t)srow * NN + scb * 8;

    const int lane = tid & 63;
    const int w    = tid >> 6;
    const int m0   = (w & 1) * 64;
    const int n0   = (w >> 1) * 64;
    const int lr   = lane & 15;
    const int lk   = lane >> 4;

    f32x4 acc[4][4];
    #pragma unroll
    for (int i = 0; i < 4; ++i)
        #pragma unroll
        for (int j = 0; j < 4; ++j)
            acc[i][j] = (f32x4){0.f, 0.f, 0.f, 0.f};

    float4 ra[4], rb[4];

    auto load_stage = [&](int st) {
        #pragma unroll
        for (int it = 0; it < 4; ++it) {
            const float* p = gp + (size_t)it * 32 * NN + (size_t)st * 64;
            ra[it] = *(const float4*)p;
            rb[it] = *(const float4*)(p + 4);
        }
    };

    auto store_stage = [&](int buf) {
        #pragma unroll
        for (int it = 0; it < 4; ++it) {
            int r = srow + 32 * it;
            short8 v = { f2bf(ra[it].x), f2bf(ra[it].y), f2bf(ra[it].z), f2bf(ra[it].w),
                         f2bf(rb[it].x), f2bf(rb[it].y), f2bf(rb[it].z), f2bf(rb[it].w) };
            int phys = scb ^ (r & 7);
            *(short8*)&lds[buf][r * 64 + phys * 8] = v;
        }
    };

    auto compute = [&](int buf) {
        #pragma unroll
        for (int ks = 0; ks < 2; ++ks) {
            short8 af[4], bfr[4];
            int cb = ks * 4 + lk;
            #pragma unroll
            for (int i = 0; i < 4; ++i) {
                int r = m0 + i * 16 + lr;
                af[i] = *(const short8*)&lds[buf][r * 64 + ((cb ^ (r & 7)) * 8)];
            }
            #pragma unroll
            for (int i = 0; i < 4; ++i) {
                int r = n0 + i * 16 + lr;
                bfr[i] = *(const short8*)&lds[buf][r * 64 + ((cb ^ (r & 7)) * 8)];
            }
            #pragma unroll
            for (int mi = 0; mi < 4; ++mi)
                #pragma unroll
                for (int ni = 0; ni < 4; ++ni)
                    acc[mi][ni] = __builtin_amdgcn_mfma_f32_16x16x32_bf16(
                        af[mi], bfr[ni], acc[mi][ni], 0, 0, 0);
        }
    };

    load_stage(0);
    store_stage(0);
    __syncthreads();
    for (int st = 0; st < nst; ++st) {
        int cur = st & 1;
        bool more = (st + 1 < nst);
        if (more) load_stage(st + 1);
        compute(cur);
        if (more) store_stage(cur ^ 1);
        __syncthreads();
    }

    float* op = partials + ((size_t)g * S + s) * (CC * CC);
    #pragma unroll
    for (int mi = 0; mi < 4; ++mi)
        #pragma unroll
        for (int ni = 0; ni < 4; ++ni)
            #pragma unroll
            for (int i = 0; i < 4; ++i) {
                int row = m0 + mi * 16 + lk * 4 + i;
                int col = n0 + ni * 16 + lr;
                op[row * CC + col] = acc[mi][ni][i];
            }
}

// ---------------- Reductions ----------------
__global__ __launch_bounds__(256) void reduce1_k(
    const float* __restrict__ partials, float* __restrict__ part2, int S)
{
    int b     = blockIdx.x >> 4;
    int chunk = blockIdx.x & 15;
    int t     = threadIdx.x;
    size_t e  = (size_t)chunk * 1024 + (size_t)t * 4;

    const f32x4* Pe = (const f32x4*)(partials + ((size_t)(2 * b) * S) * (CC * CC) + e);
    const f32x4* Pd = (const f32x4*)(partials + ((size_t)(2 * b + 1) * S) * (CC * CC) + e);
    const size_t stride = (size_t)CC * CC / 4;

    f32x4 ae = {0.f, 0.f, 0.f, 0.f}, ad = {0.f, 0.f, 0.f, 0.f};
    #pragma unroll 8
    for (int s2 = 0; s2 < S; ++s2) {
        ae += Pe[(size_t)s2 * stride];
        ad += Pd[(size_t)s2 * stride];
    }
    f32x4 d = ad - ae;
    float v = d[0] * d[0] + d[1] * d[1] + d[2] * d[2] + d[3] * d[3];
    #pragma unroll
    for (int off = 32; off > 0; off >>= 1) v += __shfl_down(v, off);
    __shared__ float wsum[4];
    if ((t & 63) == 0) wsum[t >> 6] = v;
    __syncthreads();
    if (t == 0) part2[b * 16 + chunk] = wsum[0] + wsum[1] + wsum[2] + wsum[3];
}

__global__ void reduce2_k(const float* __restrict__ part2, float* __restrict__ out)
{
    int b = blockIdx.x;
    int t = threadIdx.x;  // 64
    float v = (t < 16) ? part2[b * 16 + t] : 0.f;
    #pragma unroll
    for (int off = 8; off > 0; off >>= 1) v += __shfl_down(v, off);
    // denom = 4 * (HW)^2 * C^2 = 2^44 exactly
    if (t == 0) out[b] = v * (1.0f / 17592186044416.0f);
}

extern "C" void kernel_launch(void* const* d_in, const int* in_sizes, int n_in,
                              void* d_out, int out_size, void* d_ws, size_t ws_size,
                              hipStream_t stream)
{
    const float* f0 = (const float*)d_in[0];  // feat
    const float* f1 = (const float*)d_in[1];  // feat_decod
    float* out = (float*)d_out;

    const size_t packed_bytes = 32ull * 256 * 16384;   // 128 MiB
    const size_t perS = 32ull * CC * CC * 4;           // 2 MiB per k-chunk unit
    const size_t tail = 16 * 16 * 4;

    if (ws_size >= packed_bytes + perS * 16 + tail) {
        // main path: repack + contiguous gram, S = 16
        short* packed   = (short*)d_ws;
        float* partials = (float*)((char*)d_ws + packed_bytes);
        float* part2    = (float*)((char*)d_ws + packed_bytes + perS * 16);
        pack_k<<<512, 512, 0, stream>>>(f0, f1, packed);
        gram_packed_k<<<32 * 16, 256, 0, stream>>>(packed, partials, 16, 16);
        reduce1_k<<<16 * 16, 256, 0, stream>>>(partials, part2, 16);
        reduce2_k<<<16, 64, 0, stream>>>(part2, out);
    } else {
        // fallback: direct strided gram, adaptive split-K
        int S = 16;
        while (S > 1 && perS * (size_t)S + tail > ws_size) S >>= 1;
        int Kc  = NN / S;
        int nst = Kc / 64;
        float* partials = (float*)d_ws;
        float* part2    = (float*)((char*)d_ws + perS * (size_t)S);
        gram_direct_k<<<32 * S, 256, 0, stream>>>(f0, f1, partials, S, Kc, nst);
        reduce1_k<<<16 * 16, 256, 0, stream>>>(partials, part2, S);
        reduce2_k<<<16, 64, 0, stream>>>(part2, out);
    }
}

// Round 5
// 295.346 us; speedup vs baseline: 1.0788x; 1.0788x over previous
//
#include <hip/hip_runtime.h>

// GrahamLoss: B=16, C=128, HW=16384, fp32 in, fp32[16] out.
//
// v6: max-granule staging. History: read granule 128B/256B/512B per row-visit
// all capped ~2.4-2.7 TB/s delivered (DRAM page/bank thrash on 64KB-strided
// rows); occupancy 18->37% no effect; contiguous-read pack capped by its own
// 128B-granule writes. dur_us = kernel_sum + ~165us fixed harness reset.
// This version: ONE 128Kx bf16 LDS stage (128 rows x 512 cols) -> 2 KB
// contiguous per row-visit. 512-thread blocks, wave owns 16 rows, each row
// read as one coalesced 2KB instr-pair. S=8 -> 256 blocks = 1/CU. Single
// buffer (compute ~5% of stage time). Same f2bf/k-order/swizzle as passing r0.

typedef __attribute__((ext_vector_type(8))) short short8;
typedef __attribute__((ext_vector_type(4))) float f32x4;

#define CC 128
#define NN 16384
#define BK 512   // k-cols per stage (f32 in global, bf16 in LDS)

// fp32 -> bf16 round-to-nearest-even (bit math; inputs are finite)
__device__ __forceinline__ short f2bf(float x) {
    unsigned u = __builtin_bit_cast(unsigned, x);
    u += 0x7fffu + ((u >> 16) & 1u);
    return (short)(u >> 16);
}

__global__ __launch_bounds__(512, 2) void gram_k(
    const float* __restrict__ f0, const float* __restrict__ f1,
    float* __restrict__ partials, int S, int Kc, int nst)
{
    // single buffer: 128 rows x 512 bf16 = 128 KB; 16B chunks swizzled phys = c ^ (r&7)
    __shared__ short lds[CC * BK];

    const int tid = threadIdx.x;
    const int bx  = blockIdx.x;
    const int g   = bx & 31;   // gram id: batch*2 + src
    const int s   = bx >> 5;   // k-chunk

    const float* src  = (g & 1) ? f1 : f0;
    const float* base = src + (size_t)(g >> 1) * ((size_t)CC * NN) + (size_t)s * Kc;

    const int lane = tid & 63;
    const int w    = tid >> 6;          // wave 0..7
    const int m0   = (w & 1) * 64;      // 64-row half
    const int n0   = (w >> 1) * 32;     // 32-col quarter
    const int lr   = lane & 15;
    const int lk   = lane >> 4;

    f32x4 acc[4][2];
    #pragma unroll
    for (int i = 0; i < 4; ++i)
        #pragma unroll
        for (int j = 0; j < 2; ++j)
            acc[i][j] = (f32x4){0.f, 0.f, 0.f, 0.f};

    for (int st = 0; st < nst; ++st) {
        const float* sb = base + (size_t)st * BK;

        // ---- stage: wave w loads rows [w*16, w*16+16), 2 KB contiguous per row ----
        #pragma unroll
        for (int grp = 0; grp < 4; ++grp) {
            float4 va[4], vb[4];
            #pragma unroll
            for (int q = 0; q < 4; ++q) {
                const int r = w * 16 + grp * 4 + q;
                const float* rp = sb + (size_t)r * NN + lane * 8;
                va[q] = *(const float4*)rp;
                vb[q] = *(const float4*)(rp + 4);
            }
            #pragma unroll
            for (int q = 0; q < 4; ++q) {
                const int r = w * 16 + grp * 4 + q;
                short8 v = { f2bf(va[q].x), f2bf(va[q].y), f2bf(va[q].z), f2bf(va[q].w),
                             f2bf(vb[q].x), f2bf(vb[q].y), f2bf(vb[q].z), f2bf(vb[q].w) };
                const int phys = lane ^ (r & 7);   // 16B-chunk swizzle
                *(short8*)&lds[r * BK + phys * 8] = v;
            }
        }
        __syncthreads();

        // ---- compute: 16 k-steps of 32 over the 512-col stage ----
        #pragma unroll
        for (int ks = 0; ks < BK / 32; ++ks) {
            short8 af[4], bf2[2];
            const int c = ks * 4 + lk;             // 16B chunk index (0..63)
            #pragma unroll
            for (int i = 0; i < 4; ++i) {
                const int r = m0 + i * 16 + lr;
                af[i] = *(const short8*)&lds[r * BK + ((c ^ (r & 7)) * 8)];
            }
            #pragma unroll
            for (int j = 0; j < 2; ++j) {
                const int r = n0 + j * 16 + lr;
                bf2[j] = *(const short8*)&lds[r * BK + ((c ^ (r & 7)) * 8)];
            }
            #pragma unroll
            for (int mi = 0; mi < 4; ++mi)
                #pragma unroll
                for (int ni = 0; ni < 2; ++ni)
                    acc[mi][ni] = __builtin_amdgcn_mfma_f32_16x16x32_bf16(
                        af[mi], bf2[ni], acc[mi][ni], 0, 0, 0);
        }
        __syncthreads();
    }

    // epilogue: write partial gram (consistent bijective lane->slot map)
    float* op = partials + ((size_t)g * S + s) * (CC * CC);
    #pragma unroll
    for (int mi = 0; mi < 4; ++mi)
        #pragma unroll
        for (int ni = 0; ni < 2; ++ni)
            #pragma unroll
            for (int i = 0; i < 4; ++i) {
                const int row = m0 + mi * 16 + lk * 4 + i;
                const int col = n0 + ni * 16 + lr;
                op[row * CC + col] = acc[mi][ni][i];
            }
}

__global__ __launch_bounds__(256) void reduce1_k(
    const float* __restrict__ partials, float* __restrict__ part2, int S)
{
    int b     = blockIdx.x >> 4;   // batch
    int chunk = blockIdx.x & 15;   // 1024-entry chunk of the 16384-entry gram
    int t     = threadIdx.x;
    size_t e  = (size_t)chunk * 1024 + (size_t)t * 4;

    const f32x4* Pe = (const f32x4*)(partials + ((size_t)(2 * b) * S) * (CC * CC) + e);
    const f32x4* Pd = (const f32x4*)(partials + ((size_t)(2 * b + 1) * S) * (CC * CC) + e);
    const size_t stride = (size_t)CC * CC / 4;

    f32x4 ae = {0.f, 0.f, 0.f, 0.f}, ad = {0.f, 0.f, 0.f, 0.f};
    #pragma unroll 8
    for (int s2 = 0; s2 < S; ++s2) {
        ae += Pe[(size_t)s2 * stride];
        ad += Pd[(size_t)s2 * stride];
    }
    f32x4 d = ad - ae;
    float v = d[0] * d[0] + d[1] * d[1] + d[2] * d[2] + d[3] * d[3];
    #pragma unroll
    for (int off = 32; off > 0; off >>= 1) v += __shfl_down(v, off);
    __shared__ float wsum[4];
    if ((t & 63) == 0) wsum[t >> 6] = v;
    __syncthreads();
    if (t == 0) part2[b * 16 + chunk] = wsum[0] + wsum[1] + wsum[2] + wsum[3];
}

__global__ void reduce2_k(const float* __restrict__ part2, float* __restrict__ out)
{
    int b = blockIdx.x;
    int t = threadIdx.x;  // 64
    float v = (t < 16) ? part2[b * 16 + t] : 0.f;
    #pragma unroll
    for (int off = 8; off > 0; off >>= 1) v += __shfl_down(v, off);
    // denom = 4 * (HW)^2 * C^2 = 2^44 exactly
    if (t == 0) out[b] = v * (1.0f / 17592186044416.0f);
}

extern "C" void kernel_launch(void* const* d_in, const int* in_sizes, int n_in,
                              void* d_out, int out_size, void* d_ws, size_t ws_size,
                              hipStream_t stream)
{
    const float* f0 = (const float*)d_in[0];  // feat
    const float* f1 = (const float*)d_in[1];  // feat_decod
    float* out = (float*)d_out;

    // adaptive split-K: S power of 2 <= 8 such that partials fit in ws
    const size_t perS = 32ull * CC * CC * 4;  // 2 MiB per k-chunk unit (32 grams)
    const size_t tail = 16 * 16 * 4;
    int S = 8;
    while (S > 1 && perS * (size_t)S + tail > ws_size) S >>= 1;
    int Kc  = NN / S;
    int nst = Kc / BK;

    float* partials = (float*)d_ws;
    float* part2    = (float*)((char*)d_ws + perS * (size_t)S);

    gram_k<<<32 * S, 512, 0, stream>>>(f0, f1, partials, S, Kc, nst);
    reduce1_k<<<16 * 16, 256, 0, stream>>>(partials, part2, S);
    reduce2_k<<<16, 64, 0, stream>>>(part2, out);
}